// Round 6
// baseline (287.834 us; speedup 1.0000x reference)
//
#include <hip/hip_runtime.h>
#include <hip/hip_bf16.h>
#include <math.h>

// N=500,000 nodes, E=16,000,000 edges, D_COEF=1, EPS=1e-12.
// Outputs (fp32, flat): v [N,2] then torque [N,1].
// torque = w0 * sum_sin / max(||sum||, eps)  (count cancels in normalize).
//
// R2: global fp32 atomics = ~32B memory-side RMW each -> binning.
// R3: two-phase binning -> 408 us.  R4: LDS counting-sort + packed u64 LDS
// atomics -> 278.  R5: theta carried in the entry (local_dst:11|theta_q:21)
// -> phase 2 is a pure stream (~32 us), phase 1 absorbed the gather and is
// latency-bound at 28% occupancy (45 KB LDS -> 3 blocks/CU). Fixed ~90 us
// harness overhead sits under everything.
// R6: K_BATCH 8192->4096, EPT 32->16: LDS 24 KB -> 6 blocks/CU (75% occ).
//     Cursor array padded to 64B stride to kill cacheline contention on the
//     ~1M global cursor atomics (stride runtime-selected by ws_size).
//
// ws layout: [0..16K) uint cursors (stride CS), then uint bins[NB * CAP].

#define NBITS_Q   21
#define Q_MASK    ((1u << NBITS_Q) - 1)
#define Q_SCALE   131072.0f            // 2^21 / 16
#define Q_INV     (1.0f / 131072.0f)
#define BIN_SHIFT 11
#define BIN_W     2048
#define NB        245                  // ceil(500000/2048)
#define CAP       67584                // mean 65306 + ~9 sigma, mult of 4
#define K_BATCH   4096                 // edges per phase-1 block
#define EPT       16                   // edges per thread, phase 1
#define SCALE_F   524288.0f            // 2^19 (phase-2 fixed-point)
#define INV_SCALE (1.0f / 524288.0f)

__global__ void init_cursors(unsigned* __restrict__ cur, int cs) {
    int b = blockIdx.x * blockDim.x + threadIdx.x;
    if (b < 256) cur[b * cs] = (b < NB) ? (unsigned)b * CAP : 0u;
}

__global__ __launch_bounds__(256) void bin_edges_sort(
        const float* __restrict__ theta,
        const int4* __restrict__ src4, const int4* __restrict__ dst4,
        unsigned* __restrict__ bins, unsigned* __restrict__ cursor, int cs,
        int E)
{
    __shared__ unsigned      sorted[K_BATCH];   // 16 KB
    __shared__ unsigned char sbin[K_BATCH];     //  4 KB
    __shared__ unsigned      hist[256];
    __shared__ unsigned      base[256];
    __shared__ unsigned      gbase[256];
    __shared__ unsigned      lcnt[256];         // 4 KB total scalars -> 24 KB

    const int tid   = threadIdx.x;
    const int bb    = blockIdx.x;
    const int e0    = bb * K_BATCH;
    const int nval  = min(K_BATCH, E - e0);
    const int E4    = E >> 2;
    const int base4 = e0 >> 2;

    hist[tid] = 0;
    lcnt[tid] = 0;
    __syncthreads();

    // ---- A: load all src quads, then issue all 16 theta gathers (MLP) ----
    int4 sQ[EPT / 4];
#pragma unroll
    for (int j = 0; j < EPT / 4; ++j) {
        const int idx4 = base4 + j * 256 + tid;
        sQ[j] = (idx4 < E4) ? src4[idx4] : make_int4(0, 0, 0, 0);
    }
    float tq[EPT];
#pragma unroll
    for (int j = 0; j < EPT / 4; ++j) {
        tq[j * 4 + 0] = theta[sQ[j].x];
        tq[j * 4 + 1] = theta[sQ[j].y];
        tq[j * 4 + 2] = theta[sQ[j].z];
        tq[j * 4 + 3] = theta[sQ[j].w];
    }

    // ---- B: load dst quads, build entries, histogram ----
    unsigned      ent[EPT];
    unsigned char bn[EPT];     // bin id, 0xFF = invalid (NB=245 < 255)
#pragma unroll
    for (int j = 0; j < EPT / 4; ++j) {
        const int idx4 = base4 + j * 256 + tid;
        const int q0   = j * 4;
        if (idx4 < E4) {
            const int4 d = dst4[idx4];
            const int dd[4] = {d.x, d.y, d.z, d.w};
#pragma unroll
            for (int k = 0; k < 4; ++k) {
                const unsigned b = (unsigned)dd[k] >> BIN_SHIFT;
                float qf = (tq[q0 + k] + 8.0f) * Q_SCALE + 0.5f;
                qf = fminf(fmaxf(qf, 0.0f), 2097151.0f);
                ent[q0 + k] = ((unsigned)(dd[k] & (BIN_W - 1)) << NBITS_Q)
                              | (unsigned)qf;
                bn[q0 + k]  = (unsigned char)b;
                atomicAdd(&hist[b], 1u);
            }
        } else {
#pragma unroll
            for (int k = 0; k < 4; ++k) bn[q0 + k] = 0xFFu;
        }
    }
    __syncthreads();

    // ---- C: exclusive prefix scan of hist (Hillis-Steele over 256) ----
    const unsigned x = hist[tid];
    base[tid] = x;
    __syncthreads();
    for (int off = 1; off < 256; off <<= 1) {
        const unsigned y = (tid >= off) ? base[tid - off] : 0u;
        __syncthreads();
        base[tid] += y;
        __syncthreads();
    }
    const unsigned excl = base[tid] - x;
    __syncthreads();
    base[tid] = excl;
    if (x) gbase[tid] = atomicAdd(&cursor[tid * cs], x);  // reserve global run
    __syncthreads();

    // ---- D: scatter into sorted LDS buffer ----
#pragma unroll
    for (int q = 0; q < EPT; ++q) {
        if (bn[q] != 0xFFu) {
            const unsigned b   = bn[q];
            const unsigned pos = base[b] + atomicAdd(&lcnt[b], 1u);
            sorted[pos] = ent[q];
            sbin[pos]   = (unsigned char)b;
        }
    }
    __syncthreads();

    // ---- E: coalesced write-out (contiguous run per bin) ----
    for (int l = tid; l < nval; l += 256) {
        const unsigned b    = sbin[l];
        const unsigned gpos = gbase[b] + ((unsigned)l - base[b]);
        if (gpos < (b + 1u) * CAP)          // ~9-sigma overflow guard
            bins[gpos] = sorted[l];
    }
}

__global__ __launch_bounds__(1024) void reduce_bins(
        const float* __restrict__ theta, const unsigned* __restrict__ bins,
        const unsigned* __restrict__ cursor, int cs,
        const float* __restrict__ v0p, const float* __restrict__ w0p,
        float* __restrict__ out, int N)
{
    __shared__ float th[BIN_W];                         //  8 KB
    __shared__ unsigned long long acc[BIN_W];           // 16 KB
    const int b     = blockIdx.x;
    const int tid   = threadIdx.x;
    const int node0 = b * BIN_W;
    const int W     = min(BIN_W, N - node0);

    for (int j = tid; j < BIN_W; j += 1024) {
        th[j]  = (j < W) ? theta[node0 + j] : 0.f;
        acc[j] = 0ull;
    }
    __syncthreads();

    const unsigned  base  = (unsigned)b * CAP;
    const int       count = (int)(cursor[b * cs] - base);
    const unsigned* bp    = bins + base;

    // stream 8 entries/thread/iter via two unit-stride uint4 loads
    const int CH = 1024 * 8;
    int i0 = 0;
    for (; i0 + CH <= count; i0 += CH) {
        const uint4 ea = *(const uint4*)(bp + i0 + tid * 4);
        const uint4 eb = *(const uint4*)(bp + i0 + 4096 + tid * 4);
        const unsigned ee[8] = {ea.x, ea.y, ea.z, ea.w, eb.x, eb.y, eb.z, eb.w};
#pragma unroll
        for (int k = 0; k < 8; ++k) {
            const unsigned e = ee[k];
            const unsigned l = e >> NBITS_Q;
            const float ts = (float)(e & Q_MASK) * Q_INV - 8.0f;
            float sn, cs2;
            __sincosf(ts - th[l], &sn, &cs2);
            const unsigned cq = (unsigned)((cs2 + 1.0f) * SCALE_F + 0.5f);
            const unsigned sq = (unsigned)((sn + 1.0f) * SCALE_F + 0.5f);
            atomicAdd(&acc[l], (1ull << 56) | ((unsigned long long)cq << 28)
                               | (unsigned long long)sq);
        }
    }
    for (int i = i0 + tid; i < count; i += 1024) {
        const unsigned e = bp[i];
        const unsigned l = e >> NBITS_Q;
        const float ts = (float)(e & Q_MASK) * Q_INV - 8.0f;
        float sn, cs2;
        __sincosf(ts - th[l], &sn, &cs2);
        const unsigned cq = (unsigned)((cs2 + 1.0f) * SCALE_F + 0.5f);
        const unsigned sq = (unsigned)((sn + 1.0f) * SCALE_F + 0.5f);
        atomicAdd(&acc[l], (1ull << 56) | ((unsigned long long)cq << 28)
                           | (unsigned long long)sq);
    }
    __syncthreads();

    // epilogue: unpack, v and torque (th[] is exact fp32 theta)
    const float v0 = *v0p, w0 = *w0p;
    for (int j = tid; j < W; j += 1024) {
        const float t = th[j];
        float sn, cs2;
        __sincosf(t, &sn, &cs2);
        ((float2*)out)[node0 + j] = make_float2(v0 * cs2, v0 * sn);
        const unsigned long long P = acc[j];
        const float c  = (float)(unsigned)(P >> 56);
        const float xs = (float)(unsigned)((P >> 28) & 0xFFFFFFFull) * INV_SCALE - c;
        const float ys = (float)(unsigned)(P & 0xFFFFFFFull) * INV_SCALE - c;
        const float nrm = sqrtf(xs * xs + ys * ys);
        out[2 * N + node0 + j] = w0 * (ys / fmaxf(nrm, 1e-12f));
    }
}

// ---------- fallback path (round-2 kernels) if ws is too small ----------

__global__ void zero_ws_kernel(float4* __restrict__ ws, int n4) {
    int i = blockIdx.x * blockDim.x + threadIdx.x;
    if (i < n4) ws[i] = make_float4(0.f, 0.f, 0.f, 0.f);
}

__global__ void edge_kernel_fb(const float* __restrict__ theta,
                               const int4* __restrict__ src4,
                               const int4* __restrict__ dst4,
                               float2* __restrict__ acc, int E8) {
    int i = blockIdx.x * blockDim.x + threadIdx.x;
    if (i >= E8) return;
    const int4 s0 = src4[2 * i], s1 = src4[2 * i + 1];
    const int4 d0 = dst4[2 * i], d1 = dst4[2 * i + 1];
    const int ss[8] = {s0.x, s0.y, s0.z, s0.w, s1.x, s1.y, s1.z, s1.w};
    const int dd[8] = {d0.x, d0.y, d0.z, d0.w, d1.x, d1.y, d1.z, d1.w};
    float ts[8], td[8];
#pragma unroll
    for (int k = 0; k < 8; ++k) ts[k] = theta[ss[k]];
#pragma unroll
    for (int k = 0; k < 8; ++k) td[k] = theta[dd[k]];
#pragma unroll
    for (int k = 0; k < 8; ++k) {
        float sn, cs;
        __sincosf(ts[k] - td[k], &sn, &cs);
        atomicAdd(&acc[dd[k]].x, cs);
        atomicAdd(&acc[dd[k]].y, sn);
    }
}

__global__ void node_kernel_fb(const float* __restrict__ theta,
                               const float2* __restrict__ acc,
                               const float* __restrict__ v0p,
                               const float* __restrict__ w0p,
                               float* __restrict__ out, int N) {
    int i = blockIdx.x * blockDim.x + threadIdx.x;
    if (i >= N) return;
    const float v0 = *v0p, w0 = *w0p;
    float sn, cs;
    __sincosf(theta[i], &sn, &cs);
    ((float2*)out)[i] = make_float2(v0 * cs, v0 * sn);
    const float2 a = acc[i];
    const float nrm = sqrtf(a.x * a.x + a.y * a.y);
    out[2 * N + i] = w0 * (a.y / fmaxf(nrm, 1e-12f));
}

extern "C" void kernel_launch(void* const* d_in, const int* in_sizes, int n_in,
                              void* d_out, int out_size, void* d_ws, size_t ws_size,
                              hipStream_t stream) {
    const float* theta = (const float*)d_in[0];
    const int*   src   = (const int*)d_in[1];
    const int*   dst   = (const int*)d_in[2];
    const float* v0p   = (const float*)d_in[3];
    const float* w0p   = (const float*)d_in[4];
    float*       out   = (float*)d_out;

    const int N = in_sizes[0];   // 500,000
    const int E = in_sizes[1];   // 16,000,000

    const size_t bins_bytes = (size_t)NB * CAP * sizeof(unsigned);
    const size_t need16 = 16384 + bins_bytes;   // 64B-strided cursors
    const size_t need1  = 1024  + bins_bytes;   // packed cursors

    if ((ws_size >= need1) && N <= NB * BIN_W) {
        const int cs = (ws_size >= need16) ? 16 : 1;     // cursor stride
        unsigned* cursor = (unsigned*)d_ws;
        unsigned* bins   = cursor + ((cs == 16) ? 4096 : 256);

        init_cursors<<<1, 256, 0, stream>>>(cursor, cs);

        const int nblk = (E + K_BATCH - 1) / K_BATCH;   // 3907
        bin_edges_sort<<<nblk, 256, 0, stream>>>(theta, (const int4*)src,
                                                 (const int4*)dst,
                                                 bins, cursor, cs, E);

        const int nbins = (N + BIN_W - 1) / BIN_W;      // 245
        reduce_bins<<<nbins, 1024, 0, stream>>>(theta, bins, cursor, cs,
                                                v0p, w0p, out, N);
    } else {
        float2* acc = (float2*)d_ws;
        {
            const int n4 = (2 * N) / 4;
            zero_ws_kernel<<<(n4 + 255) / 256, 256, 0, stream>>>((float4*)d_ws, n4);
        }
        {
            const int E8 = E / 8;
            edge_kernel_fb<<<(E8 + 255) / 256, 256, 0, stream>>>(
                theta, (const int4*)src, (const int4*)dst, acc, E8);
        }
        node_kernel_fb<<<(N + 255) / 256, 256, 0, stream>>>(theta, acc, v0p, w0p,
                                                            out, N);
    }
}

// Round 7
// 277.190 us; speedup vs baseline: 1.0384x; 1.0384x over previous
//
#include <hip/hip_runtime.h>
#include <hip/hip_bf16.h>
#include <math.h>

// N=500,000 nodes, E=16,000,000 edges, D_COEF=1, EPS=1e-12.
// Outputs (fp32, flat): v [N,2] then torque [N,1].
// torque = w0 * sum_sin / max(||sum||, eps)  (count cancels in normalize).
//
// R2: global fp32 atomics = ~32B memory-side RMW each -> binning.
// R3: two-phase binning 408us. R4: LDS counting-sort + packed u64 LDS
// atomics 278. R5: theta carried in entry (local_dst:11|theta_q:21) ->
// phase2 pure stream ~32us; 267 total. R6: occupancy 2x -> REGRESSION
// (165 vs 144): phase 1 is machinery-bound (barriers/LDS-ops/short runs),
// not latency-bound. ~90us fixed harness overhead under everything.
// R7: K_BATCH back to 8192; rank taken from hist atomicAdd return (kills
// lcnt pass); shfl-based scan (16 barriers -> 2); run-wise write-out
// (kills sbin, 2 LDS ops/edge); LDS 36KB -> 4 blocks/CU.
//
// ws layout: [0..16K) uint cursors (stride cs), then uint bins[NB * CAP].

#define NBITS_Q   21
#define Q_MASK    ((1u << NBITS_Q) - 1)
#define Q_SCALE   131072.0f            // 2^21 / 16
#define Q_INV     (1.0f / 131072.0f)
#define BIN_SHIFT 11
#define BIN_W     2048
#define NB        245                  // ceil(500000/2048)
#define CAP       67584                // mean 65306 + ~9 sigma, mult of 4
#define K_BATCH   8192                 // edges per phase-1 block
#define EPT       32                   // edges per thread, phase 1
#define SCALE_F   524288.0f            // 2^19 (phase-2 fixed-point)
#define INV_SCALE (1.0f / 524288.0f)

__global__ void init_cursors(unsigned* __restrict__ cur, int cs) {
    int b = blockIdx.x * blockDim.x + threadIdx.x;
    if (b < 256) cur[b * cs] = (b < NB) ? (unsigned)b * CAP : 0u;
}

__global__ __launch_bounds__(256, 4) void bin_edges_sort(
        const float* __restrict__ theta,
        const int4* __restrict__ src4, const int4* __restrict__ dst4,
        unsigned* __restrict__ bins, unsigned* __restrict__ cursor, int cs,
        int E)
{
    __shared__ unsigned sorted[K_BATCH];   // 32 KB
    __shared__ unsigned hist[256];
    __shared__ unsigned basep[257];
    __shared__ unsigned gbase[256];
    __shared__ unsigned wsum[4];

    const int tid   = threadIdx.x;
    const int lane  = tid & 63;
    const int w     = tid >> 6;
    const int bb    = blockIdx.x;
    const int e0    = bb * K_BATCH;
    const int E4    = E >> 2;
    const int base4 = e0 >> 2;

    hist[tid] = 0;
    __syncthreads();

    // ---- A: src quads; issue all 32 theta gathers (consumed only in D) ----
    int4 sQ[EPT / 4];
#pragma unroll
    for (int j = 0; j < EPT / 4; ++j) {
        const int idx4 = base4 + j * 256 + tid;
        sQ[j] = (idx4 < E4) ? src4[idx4] : make_int4(0, 0, 0, 0);
    }
    float tq[EPT];
#pragma unroll
    for (int j = 0; j < EPT / 4; ++j) {
        tq[j * 4 + 0] = theta[sQ[j].x];
        tq[j * 4 + 1] = theta[sQ[j].y];
        tq[j * 4 + 2] = theta[sQ[j].z];
        tq[j * 4 + 3] = theta[sQ[j].w];
    }

    // ---- B: dst quads -> hist atomic returns in-bin rank ----
    // pk = (local_dst:11 << 17) | (rank:9 << 8) | bin:8 ; sentinel ~0u
    unsigned pk[EPT];
#pragma unroll
    for (int j = 0; j < EPT / 4; ++j) {
        const int idx4 = base4 + j * 256 + tid;
        const int q0   = j * 4;
        if (idx4 < E4) {
            const int4 d = dst4[idx4];
            const int dd[4] = {d.x, d.y, d.z, d.w};
#pragma unroll
            for (int k = 0; k < 4; ++k) {
                const unsigned b = (unsigned)dd[k] >> BIN_SHIFT;
                const unsigned r = atomicAdd(&hist[b], 1u) & 511u;
                pk[q0 + k] = ((unsigned)(dd[k] & (BIN_W - 1)) << 17)
                             | (r << 8) | b;
            }
        } else {
#pragma unroll
            for (int k = 0; k < 4; ++k) pk[q0 + k] = 0xFFFFFFFFu;
        }
    }
    __syncthreads();

    // ---- C: exclusive scan of hist (wave shfl + cross-wave), reserve ----
    {
        const unsigned x = hist[tid];
        unsigned incl = x;
#pragma unroll
        for (int off = 1; off < 64; off <<= 1) {
            const unsigned y = __shfl_up(incl, off, 64);
            if (lane >= off) incl += y;
        }
        if (lane == 63) wsum[w] = incl;
        __syncthreads();
        unsigned wo = 0;
#pragma unroll
        for (int k = 0; k < 4; ++k)
            if (k < w) wo += wsum[k];
        const unsigned excl = wo + incl - x;
        basep[tid] = excl;
        if (tid == 255) basep[256] = excl + x;
        if (x) gbase[tid] = atomicAdd(&cursor[tid * cs], x);
        __syncthreads();
    }

    // ---- D: theta has landed; build entries, scatter into sorted ----
#pragma unroll
    for (int q = 0; q < EPT; ++q) {
        const unsigned p = pk[q];
        if (p != 0xFFFFFFFFu) {
            const unsigned b    = p & 255u;
            const unsigned r    = (p >> 8) & 511u;
            const unsigned ldst = p >> 17;
            float qf = (tq[q] + 8.0f) * Q_SCALE + 0.5f;
            qf = fminf(fmaxf(qf, 0.0f), 2097151.0f);
            sorted[basep[b] + r] = (ldst << NBITS_Q) | (unsigned)qf;
        }
    }
    __syncthreads();

    // ---- E: run-wise coalesced write-out (one wave per bin run) ----
    for (int b = w; b < NB; b += 4) {
        const unsigned st  = basep[b];
        const unsigned len = basep[b + 1] - st;
        if (!len) continue;
        const unsigned gb  = gbase[b];
        const unsigned lim = (b + 1u) * CAP;    // ~9-sigma overflow guard
        for (unsigned i = lane; i < len; i += 64) {
            const unsigned gpos = gb + i;
            if (gpos < lim) bins[gpos] = sorted[st + i];
        }
    }
}

__global__ __launch_bounds__(1024) void reduce_bins(
        const float* __restrict__ theta, const unsigned* __restrict__ bins,
        const unsigned* __restrict__ cursor, int cs,
        const float* __restrict__ v0p, const float* __restrict__ w0p,
        float* __restrict__ out, int N)
{
    __shared__ float th[BIN_W];                         //  8 KB
    __shared__ unsigned long long acc[BIN_W];           // 16 KB
    const int b     = blockIdx.x;
    const int tid   = threadIdx.x;
    const int node0 = b * BIN_W;
    const int W     = min(BIN_W, N - node0);

    for (int j = tid; j < BIN_W; j += 1024) {
        th[j]  = (j < W) ? theta[node0 + j] : 0.f;
        acc[j] = 0ull;
    }
    __syncthreads();

    const unsigned  base  = (unsigned)b * CAP;
    const int       count = (int)(cursor[b * cs] - base);
    const unsigned* bp    = bins + base;

    // stream 8 entries/thread/iter via two unit-stride uint4 loads
    const int CH = 1024 * 8;
    int i0 = 0;
    for (; i0 + CH <= count; i0 += CH) {
        const uint4 ea = *(const uint4*)(bp + i0 + tid * 4);
        const uint4 eb = *(const uint4*)(bp + i0 + 4096 + tid * 4);
        const unsigned ee[8] = {ea.x, ea.y, ea.z, ea.w, eb.x, eb.y, eb.z, eb.w};
#pragma unroll
        for (int k = 0; k < 8; ++k) {
            const unsigned e = ee[k];
            const unsigned l = e >> NBITS_Q;
            const float ts = (float)(e & Q_MASK) * Q_INV - 8.0f;
            float sn, cs2;
            __sincosf(ts - th[l], &sn, &cs2);
            const unsigned cq = (unsigned)((cs2 + 1.0f) * SCALE_F + 0.5f);
            const unsigned sq = (unsigned)((sn + 1.0f) * SCALE_F + 0.5f);
            atomicAdd(&acc[l], (1ull << 56) | ((unsigned long long)cq << 28)
                               | (unsigned long long)sq);
        }
    }
    for (int i = i0 + tid; i < count; i += 1024) {
        const unsigned e = bp[i];
        const unsigned l = e >> NBITS_Q;
        const float ts = (float)(e & Q_MASK) * Q_INV - 8.0f;
        float sn, cs2;
        __sincosf(ts - th[l], &sn, &cs2);
        const unsigned cq = (unsigned)((cs2 + 1.0f) * SCALE_F + 0.5f);
        const unsigned sq = (unsigned)((sn + 1.0f) * SCALE_F + 0.5f);
        atomicAdd(&acc[l], (1ull << 56) | ((unsigned long long)cq << 28)
                           | (unsigned long long)sq);
    }
    __syncthreads();

    // epilogue: unpack, v and torque (th[] is exact fp32 theta)
    const float v0 = *v0p, w0 = *w0p;
    for (int j = tid; j < W; j += 1024) {
        const float t = th[j];
        float sn, cs2;
        __sincosf(t, &sn, &cs2);
        ((float2*)out)[node0 + j] = make_float2(v0 * cs2, v0 * sn);
        const unsigned long long P = acc[j];
        const float c  = (float)(unsigned)(P >> 56);
        const float xs = (float)(unsigned)((P >> 28) & 0xFFFFFFFull) * INV_SCALE - c;
        const float ys = (float)(unsigned)(P & 0xFFFFFFFull) * INV_SCALE - c;
        const float nrm = sqrtf(xs * xs + ys * ys);
        out[2 * N + node0 + j] = w0 * (ys / fmaxf(nrm, 1e-12f));
    }
}

// ---------- fallback path (round-2 kernels) if ws is too small ----------

__global__ void zero_ws_kernel(float4* __restrict__ ws, int n4) {
    int i = blockIdx.x * blockDim.x + threadIdx.x;
    if (i < n4) ws[i] = make_float4(0.f, 0.f, 0.f, 0.f);
}

__global__ void edge_kernel_fb(const float* __restrict__ theta,
                               const int4* __restrict__ src4,
                               const int4* __restrict__ dst4,
                               float2* __restrict__ acc, int E8) {
    int i = blockIdx.x * blockDim.x + threadIdx.x;
    if (i >= E8) return;
    const int4 s0 = src4[2 * i], s1 = src4[2 * i + 1];
    const int4 d0 = dst4[2 * i], d1 = dst4[2 * i + 1];
    const int ss[8] = {s0.x, s0.y, s0.z, s0.w, s1.x, s1.y, s1.z, s1.w};
    const int dd[8] = {d0.x, d0.y, d0.z, d0.w, d1.x, d1.y, d1.z, d1.w};
    float ts[8], td[8];
#pragma unroll
    for (int k = 0; k < 8; ++k) ts[k] = theta[ss[k]];
#pragma unroll
    for (int k = 0; k < 8; ++k) td[k] = theta[dd[k]];
#pragma unroll
    for (int k = 0; k < 8; ++k) {
        float sn, cs;
        __sincosf(ts[k] - td[k], &sn, &cs);
        atomicAdd(&acc[dd[k]].x, cs);
        atomicAdd(&acc[dd[k]].y, sn);
    }
}

__global__ void node_kernel_fb(const float* __restrict__ theta,
                               const float2* __restrict__ acc,
                               const float* __restrict__ v0p,
                               const float* __restrict__ w0p,
                               float* __restrict__ out, int N) {
    int i = blockIdx.x * blockDim.x + threadIdx.x;
    if (i >= N) return;
    const float v0 = *v0p, w0 = *w0p;
    float sn, cs;
    __sincosf(theta[i], &sn, &cs);
    ((float2*)out)[i] = make_float2(v0 * cs, v0 * sn);
    const float2 a = acc[i];
    const float nrm = sqrtf(a.x * a.x + a.y * a.y);
    out[2 * N + i] = w0 * (a.y / fmaxf(nrm, 1e-12f));
}

extern "C" void kernel_launch(void* const* d_in, const int* in_sizes, int n_in,
                              void* d_out, int out_size, void* d_ws, size_t ws_size,
                              hipStream_t stream) {
    const float* theta = (const float*)d_in[0];
    const int*   src   = (const int*)d_in[1];
    const int*   dst   = (const int*)d_in[2];
    const float* v0p   = (const float*)d_in[3];
    const float* w0p   = (const float*)d_in[4];
    float*       out   = (float*)d_out;

    const int N = in_sizes[0];   // 500,000
    const int E = in_sizes[1];   // 16,000,000

    const size_t bins_bytes = (size_t)NB * CAP * sizeof(unsigned);
    const size_t need16 = 16384 + bins_bytes;   // 64B-strided cursors
    const size_t need1  = 1024  + bins_bytes;   // packed cursors

    if ((ws_size >= need1) && N <= NB * BIN_W) {
        const int cs = (ws_size >= need16) ? 16 : 1;     // cursor stride
        unsigned* cursor = (unsigned*)d_ws;
        unsigned* bins   = cursor + ((cs == 16) ? 4096 : 256);

        init_cursors<<<1, 256, 0, stream>>>(cursor, cs);

        const int nblk = (E + K_BATCH - 1) / K_BATCH;   // 1954
        bin_edges_sort<<<nblk, 256, 0, stream>>>(theta, (const int4*)src,
                                                 (const int4*)dst,
                                                 bins, cursor, cs, E);

        const int nbins = (N + BIN_W - 1) / BIN_W;      // 245
        reduce_bins<<<nbins, 1024, 0, stream>>>(theta, bins, cursor, cs,
                                                v0p, w0p, out, N);
    } else {
        float2* acc = (float2*)d_ws;
        {
            const int n4 = (2 * N) / 4;
            zero_ws_kernel<<<(n4 + 255) / 256, 256, 0, stream>>>((float4*)d_ws, n4);
        }
        {
            const int E8 = E / 8;
            edge_kernel_fb<<<(E8 + 255) / 256, 256, 0, stream>>>(
                theta, (const int4*)src, (const int4*)dst, acc, E8);
        }
        node_kernel_fb<<<(N + 255) / 256, 256, 0, stream>>>(theta, acc, v0p, w0p,
                                                            out, N);
    }
}

// Round 8
// 272.788 us; speedup vs baseline: 1.0552x; 1.0161x over previous
//
#include <hip/hip_runtime.h>
#include <hip/hip_bf16.h>
#include <math.h>

// N=500,000 nodes, E=16,000,000 edges, D_COEF=1, EPS=1e-12.
// Outputs (fp32, flat): v [N,2] then torque [N,1].
// torque = w0 * sum_sin / max(||sum||, eps)  (count cancels in normalize).
//
// R2: global fp32 atomics = ~32B memory-side RMW -> binning.
// R3: two-phase 408us. R4: LDS counting-sort 278. R5 (champion, 267):
// theta carried in entry (local_dst:11|theta_q:21); phase2 pure stream 32us.
// R6: 2x blocks w/ half runs -> regress (write amp, 2x scans). R7: machinery
// cut (rank-from-hist, shfl scan, run writeout) -> neutral-worse (155) =>
// visible LDS/scan ops are NOT the bound. Gather ~58us (TA throughput,
// ~2.2cy/divergent lane) wherever it lives. Remaining untested variable:
// R5 ran at 28% occupancy. R8 = exact R5 structure, 512 threads x EPT16:
// same K_BATCH/runs/blocks, LDS 44KB -> 3 blocks/CU = 24 waves (75%).
//
// ws layout: [0..16K) uint cursors (stride cs), then uint bins[NB * CAP].

#define NBITS_Q   21
#define Q_MASK    ((1u << NBITS_Q) - 1)
#define Q_SCALE   131072.0f            // 2^21 / 16
#define Q_INV     (1.0f / 131072.0f)
#define BIN_SHIFT 11
#define BIN_W     2048
#define NB        245                  // ceil(500000/2048)
#define CAP       67584                // mean 65306 + ~9 sigma, mult of 4
#define K_BATCH   8192                 // edges per phase-1 block
#define P1_T      512                  // phase-1 threads
#define EPT       16                   // edges per thread (512*16 = 8192)
#define SCALE_F   524288.0f            // 2^19 (phase-2 fixed-point)
#define INV_SCALE (1.0f / 524288.0f)

__global__ void init_cursors(unsigned* __restrict__ cur, int cs) {
    int b = blockIdx.x * blockDim.x + threadIdx.x;
    if (b < 256) cur[b * cs] = (b < NB) ? (unsigned)b * CAP : 0u;
}

__global__ __launch_bounds__(P1_T, 6) void bin_edges_sort(
        const float* __restrict__ theta,
        const int4* __restrict__ src4, const int4* __restrict__ dst4,
        unsigned* __restrict__ bins, unsigned* __restrict__ cursor, int cs,
        int E)
{
    __shared__ unsigned      sorted[K_BATCH];   // 32 KB
    __shared__ unsigned char sbin[K_BATCH];     //  8 KB
    __shared__ unsigned      hist[256];
    __shared__ unsigned      base[256];
    __shared__ unsigned      gbase[256];
    __shared__ unsigned      lcnt[256];         // -> ~44 KB total

    const int tid   = threadIdx.x;
    const int bb    = blockIdx.x;
    const int e0    = bb * K_BATCH;
    const int nval  = min(K_BATCH, E - e0);
    const int E4    = E >> 2;
    const int base4 = e0 >> 2;

    if (tid < 256) { hist[tid] = 0; lcnt[tid] = 0; }
    __syncthreads();

    // ---- A: load all src quads, then issue all 16 theta gathers (MLP) ----
    int4 sQ[EPT / 4];
#pragma unroll
    for (int j = 0; j < EPT / 4; ++j) {
        const int idx4 = base4 + j * P1_T + tid;
        sQ[j] = (idx4 < E4) ? src4[idx4] : make_int4(0, 0, 0, 0);
    }
    float tq[EPT];
#pragma unroll
    for (int j = 0; j < EPT / 4; ++j) {
        tq[j * 4 + 0] = theta[sQ[j].x];
        tq[j * 4 + 1] = theta[sQ[j].y];
        tq[j * 4 + 2] = theta[sQ[j].z];
        tq[j * 4 + 3] = theta[sQ[j].w];
    }

    // ---- B: load dst quads, build entries, histogram ----
    unsigned      ent[EPT];
    unsigned char bn[EPT];     // bin id, 0xFF = invalid (NB=245 < 255)
#pragma unroll
    for (int j = 0; j < EPT / 4; ++j) {
        const int idx4 = base4 + j * P1_T + tid;
        const int q0   = j * 4;
        if (idx4 < E4) {
            const int4 d = dst4[idx4];
            const int dd[4] = {d.x, d.y, d.z, d.w};
#pragma unroll
            for (int k = 0; k < 4; ++k) {
                const unsigned b = (unsigned)dd[k] >> BIN_SHIFT;
                float qf = (tq[q0 + k] + 8.0f) * Q_SCALE + 0.5f;
                qf = fminf(fmaxf(qf, 0.0f), 2097151.0f);
                ent[q0 + k] = ((unsigned)(dd[k] & (BIN_W - 1)) << NBITS_Q)
                              | (unsigned)qf;
                bn[q0 + k]  = (unsigned char)b;
                atomicAdd(&hist[b], 1u);
            }
        } else {
#pragma unroll
            for (int k = 0; k < 4; ++k) bn[q0 + k] = 0xFFu;
        }
    }
    __syncthreads();

    // ---- C: exclusive prefix scan of hist (Hillis-Steele over 256) ----
    // all 512 threads execute the barriers; tid<256 do the work
    {
        const unsigned x = (tid < 256) ? hist[tid] : 0u;
        if (tid < 256) base[tid] = x;
        __syncthreads();
        for (int off = 1; off < 256; off <<= 1) {
            unsigned y = 0;
            if (tid < 256 && tid >= off) y = base[tid - off];
            __syncthreads();
            if (tid < 256) base[tid] += y;
            __syncthreads();
        }
        if (tid < 256) {
            const unsigned excl = base[tid] - x;
            base[tid] = excl;
            if (x) gbase[tid] = atomicAdd(&cursor[tid * cs], x);
        }
        __syncthreads();
    }

    // ---- D: scatter into sorted LDS buffer ----
#pragma unroll
    for (int q = 0; q < EPT; ++q) {
        if (bn[q] != 0xFFu) {
            const unsigned b   = bn[q];
            const unsigned pos = base[b] + atomicAdd(&lcnt[b], 1u);
            sorted[pos] = ent[q];
            sbin[pos]   = (unsigned char)b;
        }
    }
    __syncthreads();

    // ---- E: coalesced write-out (contiguous run per bin) ----
    for (int l = tid; l < nval; l += P1_T) {
        const unsigned b    = sbin[l];
        const unsigned gpos = gbase[b] + ((unsigned)l - base[b]);
        if (gpos < (b + 1u) * CAP)          // ~9-sigma overflow guard
            bins[gpos] = sorted[l];
    }
}

__global__ __launch_bounds__(1024) void reduce_bins(
        const float* __restrict__ theta, const unsigned* __restrict__ bins,
        const unsigned* __restrict__ cursor, int cs,
        const float* __restrict__ v0p, const float* __restrict__ w0p,
        float* __restrict__ out, int N)
{
    __shared__ float th[BIN_W];                         //  8 KB
    __shared__ unsigned long long acc[BIN_W];           // 16 KB
    const int b     = blockIdx.x;
    const int tid   = threadIdx.x;
    const int node0 = b * BIN_W;
    const int W     = min(BIN_W, N - node0);

    for (int j = tid; j < BIN_W; j += 1024) {
        th[j]  = (j < W) ? theta[node0 + j] : 0.f;
        acc[j] = 0ull;
    }
    __syncthreads();

    const unsigned  base  = (unsigned)b * CAP;
    const int       count = (int)(cursor[b * cs] - base);
    const unsigned* bp    = bins + base;

    // stream 8 entries/thread/iter via two unit-stride uint4 loads
    const int CH = 1024 * 8;
    int i0 = 0;
    for (; i0 + CH <= count; i0 += CH) {
        const uint4 ea = *(const uint4*)(bp + i0 + tid * 4);
        const uint4 eb = *(const uint4*)(bp + i0 + 4096 + tid * 4);
        const unsigned ee[8] = {ea.x, ea.y, ea.z, ea.w, eb.x, eb.y, eb.z, eb.w};
#pragma unroll
        for (int k = 0; k < 8; ++k) {
            const unsigned e = ee[k];
            const unsigned l = e >> NBITS_Q;
            const float ts = (float)(e & Q_MASK) * Q_INV - 8.0f;
            float sn, cs2;
            __sincosf(ts - th[l], &sn, &cs2);
            const unsigned cq = (unsigned)((cs2 + 1.0f) * SCALE_F + 0.5f);
            const unsigned sq = (unsigned)((sn + 1.0f) * SCALE_F + 0.5f);
            atomicAdd(&acc[l], (1ull << 56) | ((unsigned long long)cq << 28)
                               | (unsigned long long)sq);
        }
    }
    for (int i = i0 + tid; i < count; i += 1024) {
        const unsigned e = bp[i];
        const unsigned l = e >> NBITS_Q;
        const float ts = (float)(e & Q_MASK) * Q_INV - 8.0f;
        float sn, cs2;
        __sincosf(ts - th[l], &sn, &cs2);
        const unsigned cq = (unsigned)((cs2 + 1.0f) * SCALE_F + 0.5f);
        const unsigned sq = (unsigned)((sn + 1.0f) * SCALE_F + 0.5f);
        atomicAdd(&acc[l], (1ull << 56) | ((unsigned long long)cq << 28)
                           | (unsigned long long)sq);
    }
    __syncthreads();

    // epilogue: unpack, v and torque (th[] is exact fp32 theta)
    const float v0 = *v0p, w0 = *w0p;
    for (int j = tid; j < W; j += 1024) {
        const float t = th[j];
        float sn, cs2;
        __sincosf(t, &sn, &cs2);
        ((float2*)out)[node0 + j] = make_float2(v0 * cs2, v0 * sn);
        const unsigned long long P = acc[j];
        const float c  = (float)(unsigned)(P >> 56);
        const float xs = (float)(unsigned)((P >> 28) & 0xFFFFFFFull) * INV_SCALE - c;
        const float ys = (float)(unsigned)(P & 0xFFFFFFFull) * INV_SCALE - c;
        const float nrm = sqrtf(xs * xs + ys * ys);
        out[2 * N + node0 + j] = w0 * (ys / fmaxf(nrm, 1e-12f));
    }
}

// ---------- fallback path (round-2 kernels) if ws is too small ----------

__global__ void zero_ws_kernel(float4* __restrict__ ws, int n4) {
    int i = blockIdx.x * blockDim.x + threadIdx.x;
    if (i < n4) ws[i] = make_float4(0.f, 0.f, 0.f, 0.f);
}

__global__ void edge_kernel_fb(const float* __restrict__ theta,
                               const int4* __restrict__ src4,
                               const int4* __restrict__ dst4,
                               float2* __restrict__ acc, int E8) {
    int i = blockIdx.x * blockDim.x + threadIdx.x;
    if (i >= E8) return;
    const int4 s0 = src4[2 * i], s1 = src4[2 * i + 1];
    const int4 d0 = dst4[2 * i], d1 = dst4[2 * i + 1];
    const int ss[8] = {s0.x, s0.y, s0.z, s0.w, s1.x, s1.y, s1.z, s1.w};
    const int dd[8] = {d0.x, d0.y, d0.z, d0.w, d1.x, d1.y, d1.z, d1.w};
    float ts[8], td[8];
#pragma unroll
    for (int k = 0; k < 8; ++k) ts[k] = theta[ss[k]];
#pragma unroll
    for (int k = 0; k < 8; ++k) td[k] = theta[dd[k]];
#pragma unroll
    for (int k = 0; k < 8; ++k) {
        float sn, cs;
        __sincosf(ts[k] - td[k], &sn, &cs);
        atomicAdd(&acc[dd[k]].x, cs);
        atomicAdd(&acc[dd[k]].y, sn);
    }
}

__global__ void node_kernel_fb(const float* __restrict__ theta,
                               const float2* __restrict__ acc,
                               const float* __restrict__ v0p,
                               const float* __restrict__ w0p,
                               float* __restrict__ out, int N) {
    int i = blockIdx.x * blockDim.x + threadIdx.x;
    if (i >= N) return;
    const float v0 = *v0p, w0 = *w0p;
    float sn, cs;
    __sincosf(theta[i], &sn, &cs);
    ((float2*)out)[i] = make_float2(v0 * cs, v0 * sn);
    const float2 a = acc[i];
    const float nrm = sqrtf(a.x * a.x + a.y * a.y);
    out[2 * N + i] = w0 * (a.y / fmaxf(nrm, 1e-12f));
}

extern "C" void kernel_launch(void* const* d_in, const int* in_sizes, int n_in,
                              void* d_out, int out_size, void* d_ws, size_t ws_size,
                              hipStream_t stream) {
    const float* theta = (const float*)d_in[0];
    const int*   src   = (const int*)d_in[1];
    const int*   dst   = (const int*)d_in[2];
    const float* v0p   = (const float*)d_in[3];
    const float* w0p   = (const float*)d_in[4];
    float*       out   = (float*)d_out;

    const int N = in_sizes[0];   // 500,000
    const int E = in_sizes[1];   // 16,000,000

    const size_t bins_bytes = (size_t)NB * CAP * sizeof(unsigned);
    const size_t need16 = 16384 + bins_bytes;   // 64B-strided cursors
    const size_t need1  = 1024  + bins_bytes;   // packed cursors

    if ((ws_size >= need1) && N <= NB * BIN_W) {
        const int cs = (ws_size >= need16) ? 16 : 1;     // cursor stride
        unsigned* cursor = (unsigned*)d_ws;
        unsigned* bins   = cursor + ((cs == 16) ? 4096 : 256);

        init_cursors<<<1, 256, 0, stream>>>(cursor, cs);

        const int nblk = (E + K_BATCH - 1) / K_BATCH;   // 1954
        bin_edges_sort<<<nblk, P1_T, 0, stream>>>(theta, (const int4*)src,
                                                  (const int4*)dst,
                                                  bins, cursor, cs, E);

        const int nbins = (N + BIN_W - 1) / BIN_W;      // 245
        reduce_bins<<<nbins, 1024, 0, stream>>>(theta, bins, cursor, cs,
                                                v0p, w0p, out, N);
    } else {
        float2* acc = (float2*)d_ws;
        {
            const int n4 = (2 * N) / 4;
            zero_ws_kernel<<<(n4 + 255) / 256, 256, 0, stream>>>((float4*)d_ws, n4);
        }
        {
            const int E8 = E / 8;
            edge_kernel_fb<<<(E8 + 255) / 256, 256, 0, stream>>>(
                theta, (const int4*)src, (const int4*)dst, acc, E8);
        }
        node_kernel_fb<<<(N + 255) / 256, 256, 0, stream>>>(theta, acc, v0p, w0p,
                                                            out, N);
    }
}